// Round 14
// baseline (94.025 us; speedup 1.0000x reference)
//
#include <hip/hip_runtime.h>
#include <hip/hip_bf16.h>

#define B_ 16
#define C_ 64
#define HW_ 4096              // H*W
#define K_ 1024
#define NELEM 4194304         // B*C*H*W
#define NBLK 2048             // 32 pixels per block
#define PXB 32

typedef __attribute__((ext_vector_type(8))) short bf16x8;
typedef __attribute__((ext_vector_type(4))) float f32x4;

static __device__ __forceinline__ short f2bf(float f) {
    __hip_bfloat16 h = __float2bfloat16(f);           // RNE, native cvt
    return (short)__builtin_bit_cast(unsigned short, h);
}

// ---- kernel 1: emb -> fragment-contiguous bf16(-2*emb) + e2' + cnt=0 -----
// Layout (shorts): q*16384 + it*1024 + half*512 + (kgrp*16+prow)*8,
// where code = q*256 + it*16 + prow, dims = half*32 + kgrp*8 + j.
// Wave qd's iter-it fragments are two coalesced 16B/lane loads (a0,a1).
__global__ __launch_bounds__(256) void vq_prep(const float* __restrict__ emb,
                                               float* __restrict__ e2,
                                               short* __restrict__ emb_q,
                                               int* __restrict__ cnt) {
    const int id = blockIdx.x * 256 + threadIdx.x;    // 0..8191
    if (id == 0) *cnt = 0;
    {   // -2x scale is exact in bf16 (sign + exponent shift)
        const int code = id >> 3;
        const int c16  = id & 7;                      // 16B group in row
        const float4* src = (const float4*)(emb + (size_t)id * 8);
        float4 a = src[0], b = src[1];
        bf16x8 v;
        v[0]=f2bf(-2.f*a.x); v[1]=f2bf(-2.f*a.y); v[2]=f2bf(-2.f*a.z); v[3]=f2bf(-2.f*a.w);
        v[4]=f2bf(-2.f*b.x); v[5]=f2bf(-2.f*b.y); v[6]=f2bf(-2.f*b.z); v[7]=f2bf(-2.f*b.w);
        const int q    = code >> 8;
        const int it   = (code >> 4) & 15;
        const int prow = code & 15;
        const int half = c16 >> 2;
        const int kgrp = c16 & 3;
        const int dst  = q * 16384 + it * 1024 + half * 512 + (kgrp * 16 + prow) * 8;
        *(bf16x8*)(emb_q + dst) = v;
    }
    if (id < K_) {
        const float4* row = (const float4*)(emb + (size_t)id * C_);
        float s0 = 0.f, s1 = 0.f, s2 = 0.f, s3 = 0.f;
        #pragma unroll
        for (int i = 0; i < C_ / 4; ++i) {
            float4 v = row[i];
            s0 = fmaf(v.x, v.x, s0);
            s1 = fmaf(v.y, v.y, s1);
            s2 = fmaf(v.z, v.z, s2);
            s3 = fmaf(v.w, v.w, s3);
        }
        e2[id] = 1.0f + ((s0 + s1) + (s2 + s3));   // keeps dist' > 0
    }
}

// ---- kernel 2: fused MFMA argmin + gather + q_st + loss (+last-block) ----
// SMALL blocks for phase diversity: 2048 blocks x 256 thr x 32 px,
// 8 blocks/CU resident (100% wave cap) — independent blocks' staging /
// MFMA / epilogue phases interleave on the CU (no lockstep barriers).
// Wave qd scans its K-quadrant via direct global->reg A loads (emb_q,
// fragment-contiguous); no emb LDS, no main-loop barriers, no vmcnt asm.
//   D[row=code][col=pixel] = 1 + |e|^2 - 2 z.e  (positive)
// Select: sortable int = (bits(dist) & ~1023) | k ; argmin = v_min_i32.
__global__ __launch_bounds__(256, 6) void vq_main(const float* __restrict__ z,
                                                  const float* __restrict__ emb,
                                                  const short* __restrict__ emb_q,
                                                  const float* __restrict__ e2,
                                                  float* __restrict__ out,
                                                  float* __restrict__ psum,
                                                  int* __restrict__ cnt) {
    __shared__ short zlds[PXB * 64];   // 4 KB, [px][ch], col ^= (px&7)<<4
    __shared__ int   smin[4][PXB];
    __shared__ int   cidx[PXB];
    __shared__ float red[4];
    __shared__ int   isLast;

    const int tid  = threadIdx.x;
    const int lane = tid & 63;
    const int qd   = __builtin_amdgcn_readfirstlane(tid >> 6);  // wave = quadrant
    const int prow = lane & 15;        // code-in-tile row
    const int kgrp = lane >> 4;        // k-group 0..3

    const int blk = blockIdx.x;        // 0..2047
    const int b   = blk >> 7;          // 128 blocks per image
    const int hw0 = (blk & 127) * PXB;
    const float* zp = z + (size_t)b * C_ * HW_ + hw0;   // + c*HW_ + p

    // ---- stage z -> swizzled LDS bf16 (each thread: 8 ch of one pixel) ---
    {
        const int p  = tid & 31;
        const int c0 = tid >> 5;               // 0..7
        const float* zsrc = zp + (size_t)(c0 * 8) * HW_ + p;
        bf16x8 pack;
        #pragma unroll
        for (int i = 0; i < 8; ++i) pack[i] = f2bf(zsrc[(size_t)i * HW_]);
        const int wb = (p * 128 + ((c0 * 16) ^ ((p & 7) << 4))) >> 1;
        *(bf16x8*)(zlds + wb) = pack;
    }
    __syncthreads();

    // ---- z fragments (B operand): 2 pixel tiles x 2 K-halves ----
    bf16x8 zf[2][2];
    #pragma unroll
    for (int pt = 0; pt < 2; ++pt) {
        const int pp = pt * 16 + prow;
        #pragma unroll
        for (int ks = 0; ks < 2; ++ks) {
            const int rb = (pp * 128 + ((ks * 64 + kgrp * 16) ^ ((pp & 7) << 4))) >> 1;
            zf[pt][ks] = *(const bf16x8*)(zlds + rb);
        }
    }

    // ---- per-wave argmin over its 256-code quadrant, global->reg A ----
    const short* eq  = emb_q + qd * 16384 + lane * 8;   // + it*1024 (+512)
    const float* e2q = e2 + qd * 256 + kgrp * 4;        // + it*16
    int best[2] = {0x7FFFFFFF, 0x7FFFFFFF};

    #pragma unroll 2
    for (int it = 0; it < 16; ++it) {
        const bf16x8 a0 = *(const bf16x8*)(eq + it * 1024);
        const bf16x8 a1 = *(const bf16x8*)(eq + it * 1024 + 512);
        const f32x4  ev = *(const f32x4*)(e2q + it * 16);
        const int korg = qd * 256 + it * 16 + kgrp * 4;
        #pragma unroll
        for (int pt = 0; pt < 2; ++pt) {
            f32x4 acc = ev;
            acc = __builtin_amdgcn_mfma_f32_16x16x32_bf16(a0, zf[pt][0], acc, 0, 0, 0);
            acc = __builtin_amdgcn_mfma_f32_16x16x32_bf16(a1, zf[pt][1], acc, 0, 0, 0);
            #pragma unroll
            for (int r = 0; r < 4; ++r) {
                const int s = (__builtin_bit_cast(int, acc[r]) & ~1023) | (korg + r);
                best[pt] = min(best[pt], s);
            }
        }
    }

    // cross-lane combine over k-groups (bits 4,5 of lane)
    #pragma unroll
    for (int pt = 0; pt < 2; ++pt) {
        #pragma unroll
        for (int m = 16; m <= 32; m <<= 1)
            best[pt] = min(best[pt], __shfl_xor(best[pt], m));
        if (kgrp == 0) smin[qd][pt * 16 + prow] = best[pt];
    }
    __syncthreads();

    // cross-wave combine (4 quadrant-waves)
    if (tid < PXB) {
        int bb = min(min(smin[0][tid], smin[1][tid]),
                     min(smin[2][tid], smin[3][tid]));
        cidx[tid] = bb & 1023;
    }
    __syncthreads();

    // ---- output phase: q_st = z + (q - z), partial loss ----
    float* op = out + (size_t)b * C_ * HW_ + hw0;
    const int p  = tid & 31;
    const int c0 = tid >> 5;                  // 0..7
    const float* qrow = emb + (size_t)cidx[p] * C_;
    float sq = 0.f;
    #pragma unroll
    for (int i = 0; i < 8; ++i) {
        const int c = c0 * 8 + i;
        const float zv   = zp[(size_t)c * HW_ + p];
        const float q    = qrow[c];
        const float diff = q - zv;            // matches reference op order
        op[(size_t)c * HW_ + p] = zv + diff;  // q_st = z + (q - z)
        sq = fmaf(diff, diff, sq);
    }
    #pragma unroll
    for (int off = 32; off; off >>= 1) sq += __shfl_xor(sq, off);
    if (lane == 0) red[tid >> 6] = sq;
    __syncthreads();
    if (tid == 0) {
        psum[blk] = (red[0] + red[1]) + (red[2] + red[3]);
        __threadfence();                      // psum visible device-wide
        isLast = (atomicAdd(cnt, 1) == NBLK - 1);
    }
    __syncthreads();

    // ---- last block reduces psum -> loss (fixed order => deterministic) --
    if (isLast) {
        __threadfence();
        float s = 0.f;
        #pragma unroll
        for (int i = 0; i < 8; ++i) s += psum[i * 256 + tid];
        #pragma unroll
        for (int off = 32; off; off >>= 1) s += __shfl_xor(s, off);
        if (lane == 0) red[tid >> 6] = s;
        __syncthreads();
        if (tid == 0)
            out[NELEM] = 1.25f * ((red[0] + red[1]) + (red[2] + red[3])) / (float)NELEM;
    }
}

extern "C" void kernel_launch(void* const* d_in, const int* in_sizes, int n_in,
                              void* d_out, int out_size, void* d_ws, size_t ws_size,
                              hipStream_t stream) {
    const float* z   = (const float*)d_in[0];   // [16,64,64,64]
    const float* emb = (const float*)d_in[1];   // [1024,64]
    float* out = (float*)d_out;                 // [4194304 q_st] ++ [1 loss]

    float* psum  = (float*)d_ws;                // 2048 floats
    float* e2    = psum + NBLK;                 // 1024 floats (e2' = 1+|e|^2)
    int*   cnt   = (int*)(e2 + K_);             // 1 int (+pad to 16B)
    short* emb_q = (short*)(cnt + 4);           // 65536 bf16, fragment layout

    vq_prep<<<(K_ * C_) / (256 * 8), 256, 0, stream>>>(emb, e2, emb_q, cnt);
    vq_main<<<NBLK, 256, 0, stream>>>(z, emb, emb_q, e2, out, psum, cnt);
}

// Round 15
// 33.868 us; speedup vs baseline: 2.7762x; 2.7762x over previous
//
#include <hip/hip_runtime.h>
#include <hip/hip_bf16.h>

#define B_ 16
#define C_ 64
#define HW_ 4096              // H*W
#define K_ 1024
#define NELEM 4194304         // B*C*H*W
#define NBLK 256              // persistent: 1 block per CU
#define PXG 128               // pixels per group
#define NGRP 2                // groups per block (256 px/block)

typedef __attribute__((ext_vector_type(8))) short bf16x8;
typedef __attribute__((ext_vector_type(4))) float f32x4;
typedef unsigned int u32;

static __device__ __forceinline__ short f2bf(float f) {
    __hip_bfloat16 h = __float2bfloat16(f);           // RNE, native cvt
    return (short)__builtin_bit_cast(unsigned short, h);
}

// global -> LDS async copy, 16B per lane; dest wave-uniform base (HW adds lane*16).
static __device__ __forceinline__ void gl_lds16(const short* g, short* l) {
    __builtin_amdgcn_global_load_lds(
        (const __attribute__((address_space(1))) u32*)g,
        (__attribute__((address_space(3))) u32*)l, 16, 0, 0);
}

// ---- kernel 1: emb -> chunked fragment-contiguous bf16(-2*emb) + e2' -----
// Layout (shorts): ch*4096 + q*1024 + half*512 + (kgrp*16+prow)*8,
// code = q*256 + ch*16 + prow ; dims = half*32 + kgrp*8 + j.
// Every 512-short span is one 1KB gl_lds (64 lanes x 16B); ds_read at
// lane*16B is linear -> conflict-free, no swizzle needed.
__global__ __launch_bounds__(256) void vq_prep(const float* __restrict__ emb,
                                               float* __restrict__ e2,
                                               short* __restrict__ emb_q,
                                               int* __restrict__ cnt) {
    const int id = blockIdx.x * 256 + threadIdx.x;    // 0..8191
    if (id == 0) *cnt = 0;
    {   // -2x scale is exact in bf16 (sign + exponent shift)
        const int code = id >> 3;
        const int c16  = id & 7;                      // 16B group in row
        const float4* src = (const float4*)(emb + (size_t)id * 8);
        float4 a = src[0], b = src[1];
        bf16x8 v;
        v[0]=f2bf(-2.f*a.x); v[1]=f2bf(-2.f*a.y); v[2]=f2bf(-2.f*a.z); v[3]=f2bf(-2.f*a.w);
        v[4]=f2bf(-2.f*b.x); v[5]=f2bf(-2.f*b.y); v[6]=f2bf(-2.f*b.z); v[7]=f2bf(-2.f*b.w);
        const int q    = code >> 8;
        const int ch   = (code >> 4) & 15;
        const int prow = code & 15;
        const int half = c16 >> 2;
        const int kgrp = c16 & 3;
        const int dst  = ch * 4096 + q * 1024 + half * 512 + (kgrp * 16 + prow) * 8;
        *(bf16x8*)(emb_q + dst) = v;
    }
    if (id < K_) {
        const float4* row = (const float4*)(emb + (size_t)id * C_);
        float s0 = 0.f, s1 = 0.f, s2 = 0.f, s3 = 0.f;
        #pragma unroll
        for (int i = 0; i < C_ / 4; ++i) {
            float4 v = row[i];
            s0 = fmaf(v.x, v.x, s0);
            s1 = fmaf(v.y, v.y, s1);
            s2 = fmaf(v.z, v.z, s2);
            s3 = fmaf(v.w, v.w, s3);
        }
        e2[id] = 1.0f + ((s0 + s1) + (s2 + s3));   // keeps dist' > 0
    }
}

// ---- kernel 2: persistent fused MFMA argmin + gather + q_st + loss -------
// 256 blocks x 512 thr (1 block/CU, 8 waves). The ENTIRE bf16 codebook
// (128 KB) is staged into LDS ONCE per CU via gl_lds, then the block loops
// over 2 groups of 128 pixels. Wave (h,q): pixel-half h (64 px, zf[4][2],
// A-reuse=4) x K-quadrant q (256 codes). Argmin loop has NO barriers and
// reads A-fragments as linear conflict-free ds_read_b128.
//   D[row=code][col=pixel] = 1 + |e|^2 - 2 z.e  (positive)
// Select: sortable int = (bits(dist) & ~1023) | k ; argmin = v_min_i32.
__global__ __launch_bounds__(512, 2) void vq_main(const float* __restrict__ z,
                                                  const float* __restrict__ emb,
                                                  const short* __restrict__ emb_q,
                                                  const float* __restrict__ e2,
                                                  float* __restrict__ out,
                                                  float* __restrict__ psum,
                                                  int* __restrict__ cnt) {
    __shared__ short elds[65536];         // 128 KB: whole codebook, chunked
    __shared__ short zlds[PXG * 64];      // 16 KB, [px][ch], col ^= (px&7)<<4
    __shared__ int   smin[4][PXG];        // 2 KB
    __shared__ int   cidx[PXG];
    __shared__ float red[8];
    __shared__ int   isLast;

    const int tid  = threadIdx.x;
    const int lane = tid & 63;
    const int wave = __builtin_amdgcn_readfirstlane(tid >> 6);  // 0..7
    const int h    = wave >> 2;        // pixel half
    const int qd   = wave & 3;         // K-quadrant
    const int prow = lane & 15;
    const int kgrp = lane >> 4;

    const int blk = blockIdx.x;        // 0..255

    // ---- stage the whole codebook: 128 spans x 1KB, 16 per wave ----------
    {
        const int w16 = wave * 16;
        #pragma unroll
        for (int i = 0; i < 16; ++i) {
            const int sp = w16 + i;
            gl_lds16(emb_q + sp * 512 + lane * 8, elds + sp * 512);
        }
    }

    float sqacc = 0.f;

    #pragma unroll 1
    for (int g = 0; g < NGRP; ++g) {
        const int grp = blk * NGRP + g;        // 0..511
        const int b   = grp >> 5;              // 32 groups per image
        const int hw0 = (grp & 31) * PXG;
        const float* zp = z + (size_t)b * C_ * HW_ + hw0;   // + c*HW_ + p

        if (g > 0) __syncthreads();   // epilogue of g-1 done reading zlds/cidx

        // ---- stage z[g] -> swizzled LDS bf16 (16 ch of one pixel each) ---
        {
            const int p  = tid & 127;
            const int c0 = tid >> 7;               // 0..3
            #pragma unroll
            for (int hh = 0; hh < 2; ++hh) {
                const int cb = c0 * 16 + hh * 8;
                bf16x8 pack;
                #pragma unroll
                for (int i = 0; i < 8; ++i) pack[i] = f2bf(zp[(size_t)(cb + i) * HW_ + p]);
                const int wb = (p * 128 + ((cb * 2) ^ ((p & 7) << 4))) >> 1;
                *(bf16x8*)(zlds + wb) = pack;
            }
        }
        __syncthreads();   // zlds ready (g=0: also drains the 16 gl_lds)

        // ---- z fragments: 4 pixel tiles x 2 K-halves ----
        bf16x8 zf[4][2];
        #pragma unroll
        for (int pt = 0; pt < 4; ++pt) {
            const int pp = h * 64 + pt * 16 + prow;
            #pragma unroll
            for (int ks = 0; ks < 2; ++ks) {
                const int rb = (pp * 128 + ((ks * 64 + kgrp * 16) ^ ((pp & 7) << 4))) >> 1;
                zf[pt][ks] = *(const bf16x8*)(zlds + rb);
            }
        }

        // ---- argmin over quadrant qd: 16 chunks, no barriers -------------
        const short* eb  = elds + qd * 1024 + lane * 8;   // + ch*4096 (+512)
        const float* e2q = e2 + qd * 256 + kgrp * 4;      // + ch*16
        int best[4] = {0x7FFFFFFF, 0x7FFFFFFF, 0x7FFFFFFF, 0x7FFFFFFF};

        #pragma unroll 4
        for (int ch = 0; ch < 16; ++ch) {
            const bf16x8 a0 = *(const bf16x8*)(eb + ch * 4096);
            const bf16x8 a1 = *(const bf16x8*)(eb + ch * 4096 + 512);
            const f32x4  ev = *(const f32x4*)(e2q + ch * 16);
            const int korg = qd * 256 + ch * 16 + kgrp * 4;
            #pragma unroll
            for (int pt = 0; pt < 4; ++pt) {
                f32x4 acc = ev;
                acc = __builtin_amdgcn_mfma_f32_16x16x32_bf16(a0, zf[pt][0], acc, 0, 0, 0);
                acc = __builtin_amdgcn_mfma_f32_16x16x32_bf16(a1, zf[pt][1], acc, 0, 0, 0);
                #pragma unroll
                for (int r = 0; r < 4; ++r) {
                    const int s = (__builtin_bit_cast(int, acc[r]) & ~1023) | (korg + r);
                    best[pt] = min(best[pt], s);
                }
            }
        }

        // cross-lane combine over k-groups (bits 4,5 of lane)
        #pragma unroll
        for (int pt = 0; pt < 4; ++pt) {
            #pragma unroll
            for (int m = 16; m <= 32; m <<= 1)
                best[pt] = min(best[pt], __shfl_xor(best[pt], m));
            if (kgrp == 0) smin[qd][h * 64 + pt * 16 + prow] = best[pt];
        }
        __syncthreads();

        // cross-wave combine (4 quadrant-waves per pixel)
        if (tid < PXG) {
            int bb = min(min(smin[0][tid], smin[1][tid]),
                         min(smin[2][tid], smin[3][tid]));
            cidx[tid] = bb & 1023;
        }
        __syncthreads();

        // ---- output: q_st = z + (q - z), accumulate (q-z)^2 --------------
        float* op = out + (size_t)b * C_ * HW_ + hw0;
        const int p  = tid & 127;
        const int c0 = tid >> 7;                 // 0..3
        const float* qrow = emb + (size_t)cidx[p] * C_;
        #pragma unroll
        for (int i = 0; i < 16; ++i) {
            const int c = c0 * 16 + i;
            const float zv   = zp[(size_t)c * HW_ + p];
            const float q    = qrow[c];
            const float diff = q - zv;           // matches reference op order
            op[(size_t)c * HW_ + p] = zv + diff; // q_st = z + (q - z)
            sqacc = fmaf(diff, diff, sqacc);
        }
    }

    // ---- block loss partial ----
    #pragma unroll
    for (int off = 32; off; off >>= 1) sqacc += __shfl_xor(sqacc, off);
    if (lane == 0) red[wave] = sqacc;
    __syncthreads();
    if (tid == 0) {
        float s = 0.f;
        #pragma unroll
        for (int w2 = 0; w2 < 8; ++w2) s += red[w2];
        psum[blk] = s;
        __threadfence();
        isLast = (atomicAdd(cnt, 1) == NBLK - 1);
    }
    __syncthreads();

    // ---- last block reduces psum -> loss (fixed order => deterministic) --
    if (isLast) {
        __threadfence();
        float s = (tid < NBLK) ? psum[tid] : 0.f;
        #pragma unroll
        for (int off = 32; off; off >>= 1) s += __shfl_xor(s, off);
        if (lane == 0) red[wave] = s;
        __syncthreads();
        if (tid == 0) {
            float t = 0.f;
            #pragma unroll
            for (int w2 = 0; w2 < 8; ++w2) t += red[w2];
            out[NELEM] = 1.25f * t / (float)NELEM;
        }
    }
}

extern "C" void kernel_launch(void* const* d_in, const int* in_sizes, int n_in,
                              void* d_out, int out_size, void* d_ws, size_t ws_size,
                              hipStream_t stream) {
    const float* z   = (const float*)d_in[0];   // [16,64,64,64]
    const float* emb = (const float*)d_in[1];   // [1024,64]
    float* out = (float*)d_out;                 // [4194304 q_st] ++ [1 loss]

    float* psum  = (float*)d_ws;                // 256 floats
    float* e2    = psum + NBLK;                 // 1024 floats (e2' = 1+|e|^2)
    int*   cnt   = (int*)(e2 + K_);             // 1 int (+pad)
    short* emb_q = (short*)(cnt + 4);           // 65536 bf16, chunked fragments

    vq_prep<<<(K_ * C_) / (256 * 8), 256, 0, stream>>>(emb, e2, emb_q, cnt);
    vq_main<<<NBLK, 512, 0, stream>>>(z, emb, emb_q, e2, out, psum, cnt);
}